// Round 13
// baseline (119.825 us; speedup 1.0000x reference)
//
#include <hip/hip_runtime.h>

enum { B_ = 32, T_ = 1024, V_ = 512, S_ = 128 };

static constexpr float K2   = 1.4426950408889634f;  // 1/ln2
static constexpr float LN2F = 0.6931471805599453f;
#define BOOSTI 6   // probs carry a 2^6 boost per emission so alpha drift ~0

typedef float f32x4 __attribute__((ext_vector_type(4)));
#define AS1 __attribute__((address_space(1)))
#define AS3 __attribute__((address_space(3)))

// DPP helpers
#define DPPI(x, ctrl) __builtin_amdgcn_update_dpp(0, (x), (ctrl), 0xF, 0xF, true)
#define DPPF(x, ctrl) __int_as_float(DPPI(__float_as_int(x), (ctrl)))
#define DPP_WSR1(x) DPPF((x), 0x138)   // lane l <- lane l-1, lane 0 <- 0

__device__ __forceinline__ float rdlane63f(float x) {
  return __int_as_float(__builtin_amdgcn_readlane(__float_as_int(x), 63));
}
__device__ __forceinline__ float dpp_wave_max_l63(float x) {
  x = fmaxf(x, DPPF(x, 0xB1));   x = fmaxf(x, DPPF(x, 0x4E));
  x = fmaxf(x, DPPF(x, 0x124));  x = fmaxf(x, DPPF(x, 0x128));
  x = fmaxf(x, DPPF(x, 0x142));  x = fmaxf(x, DPPF(x, 0x143));
  return x;
}

// Kernel A: per (b,t) fused logsumexp + masked linear-prob table.
// Q[b][t][lane] = (pe1*v1, pe3*v3, pb*v0, pb*v2); row = 64 f32x4 = 1024 B.
__global__ __launch_bounds__(256) void ctc_pre4(
    const float* __restrict__ logits, const int* __restrict__ targets,
    const int* __restrict__ tgtlen, f32x4* __restrict__ Q) {
  const int w = threadIdx.x >> 6, l = threadIdx.x & 63;
  const int row = blockIdx.x * 4 + w;          // row = b*T + t
  const int b = row >> 10;
  const float* lrow = logits + (size_t)row * V_;
  const float4* r4 = (const float4*)lrow;
  float4 a = r4[l], c = r4[l + 64];
  float s = __builtin_exp2f(a.x * K2) + __builtin_exp2f(a.y * K2) +
            __builtin_exp2f(a.z * K2) + __builtin_exp2f(a.w * K2) +
            __builtin_exp2f(c.x * K2) + __builtin_exp2f(c.y * K2) +
            __builtin_exp2f(c.z * K2) + __builtin_exp2f(c.w * K2);
  #pragma unroll
  for (int off = 32; off; off >>= 1) s += __shfl_xor(s, off, 64);
  const float sh = (float)BOOSTI - __builtin_log2f(s);

  const int2 ee = ((const int2*)(targets + b * S_))[l];
  const int tl = tgtlen[b];
  const float lgb = __shfl(a.x, 0, 64);        // blank logit (elem 0)
  const float lg1 = lrow[ee.x];
  const float lg3 = lrow[ee.y];
  const float pb  = __builtin_exp2f(fmaf(lgb, K2, sh));
  const float pe1 = __builtin_exp2f(fmaf(lg1, K2, sh));
  const float pe3 = __builtin_exp2f(fmaf(lg3, K2, sh));
  const int smax = 2 * tl;
  f32x4 q;
  q.x = (4 * l + 1 <= smax) ? pe1 : 0.0f;
  q.y = (4 * l + 3 <= smax) ? pe3 : 0.0f;
  q.z = (4 * l     <= smax) ? pb  : 0.0f;
  q.w = (4 * l + 2 <= smax) ? pb  : 0.0f;
  Q[(size_t)row * 64 + l] = q;
}

// Kernel B: DP over the table. 8 batches per block (8 waves = 2 waves/SIMD for
// TLP); each wave runs the R9-proven per-step pipeline on its private 16-slot
// LDS ring: GLL lead 16, DSR lead 8 into a mod-8 register file, per-step
// s_waitcnt vmcnt(7) lgkmcnt(7) (counters are per-wave). No cross-wave sync.
__global__ __launch_bounds__(512, 1) void ctc_dp4(
    const f32x4* __restrict__ Q, const int* __restrict__ targets,
    const int* __restrict__ loglen, const int* __restrict__ tgtlen,
    float* __restrict__ out) {
  __shared__ f32x4 ring[8][16 * 64];   // 8 waves x 16 slots x 1 KiB = 128 KiB
  __shared__ float A[8][260];
  const int w = threadIdx.x >> 6, l = threadIdx.x & 63;
  const int b = blockIdx.x * 8 + w;
  const int len = loglen[b], tl = tgtlen[b];

  const int2 ee = ((const int2*)(targets + b * S_))[l];
  const int e1 = ee.x, e3 = ee.y;
  const int em1 = __shfl_up(e3, 1);
  const float m1 = ((l > 0) && (e1 != 0) && (e1 != em1)) ? 1.0f : 0.0f;
  const float m3 = ((e3 != 0) && (e3 != e1)) ? 1.0f : 0.0f;
  const float v4 = (2 * tl >= 256) ? 1.0f : 0.0f;
  const f32x4* Qb = Q + (size_t)b * T_ * 64;

  // t = 0 init straight from the table
  f32x4 qi = Qb[l];
  float p0 = (l == 0) ? qi.z : 0.0f;
  float p1 = (l == 0) ? qi.x : 0.0f;
  float p2 = 0.0f, p3 = 0.0f, p4 = 0.0f;

  const unsigned rbase = (unsigned)(uintptr_t)(AS3 char*)(void*)&ring[w][0];
  const unsigned lofs  = rbase + (unsigned)l * 16u;

  asm volatile("s_waitcnt vmcnt(0) lgkmcnt(0)" ::: "memory");

#define GLL(ROW, SLOT) __builtin_amdgcn_global_load_lds( \
      (const AS1 void*)(const void*)(Qb + (size_t)(ROW) * 64 + l), \
      (AS3 void*)(void*)(&ring[w][(SLOT) * 64]), 16, 0, 0)

  // prologue: rows 1..16 -> slots (row & 15)
  GLL(1, 1);   GLL(2, 2);   GLL(3, 3);   GLL(4, 4);
  GLL(5, 5);   GLL(6, 6);   GLL(7, 7);   GLL(8, 8);
  GLL(9, 9);   GLL(10, 10); GLL(11, 11); GLL(12, 12);
  GLL(13, 13); GLL(14, 14); GLL(15, 15); GLL(16, 0);
  asm volatile("s_waitcnt vmcnt(8)" ::: "memory");   // rows 1..8 landed

  // 8-deep register file: q<g> holds the row with (row & 7) == g
  f32x4 q0, q1, q2, q3, q4, q5, q6, q7;
#define DSR(dst, SLOT) asm volatile("ds_read_b128 %0, %1" \
      : "=&v"(dst) : "v"(lofs + (unsigned)(SLOT) * 1024u))
  DSR(q1, 1); DSR(q2, 2); DSR(q3, 3); DSR(q4, 4);
  DSR(q5, 5); DSR(q6, 6); DSR(q7, 7); DSR(q0, 8);

#define COMPUTE(RX) { \
    const float n1_  = DPP_WSR1(p3); \
    const float bc_  = rdlane63f(p3); \
    const float pbl_ = rdlane63f(RX.w); \
    const float w0_ = (p0 + n1_) * RX.z; \
    const float w1_ = (p0 + p1 + n1_ * m1) * RX.x; \
    const float w2_ = (p1 + p2) * RX.w; \
    const float w3_ = (p2 + p3 + p1 * m3) * RX.y; \
    const float w4_ = (p4 + bc_) * (pbl_ * v4); \
    p0 = w0_; p1 = w1_; p2 = w2_; p3 = w3_; p4 = w4_; \
  }

  // step i (row r = t+i, t ≡ 1 mod 16): wait so GLL for the slot this step's
  // DSR reads (row r+8) and DSR for row r are complete; consume reg R; refill
  // slot (r&15) with row r+16; DSR row r+8 into the same register R.
#define STEPM(i, R, DSLOT, GSLOT) { \
    asm volatile("s_waitcnt vmcnt(7) lgkmcnt(7)" : "+v"(R) :: "memory"); \
    COMPUTE(R); \
    int row_ = t + (i) + 16; if (row_ > T_ - 1) row_ = T_ - 1; \
    GLL(row_, GSLOT); \
    DSR(R, DSLOT); \
  }

#define RENORM { \
    float m_ = fmaxf(fmaxf(fmaxf(p0, p1), fmaxf(p2, p3)), p4); \
    m_ = dpp_wave_max_l63(m_); \
    const int wm_ = __builtin_amdgcn_readlane(__float_as_int(m_), 63); \
    const int e_ = (wm_ >> 23) & 0xFF; \
    const float sc_ = __int_as_float((254 - e_) << 23); \
    p0 *= sc_; p1 *= sc_; p2 *= sc_; p3 *= sc_; p4 *= sc_; \
    shift += e_ - 127; \
  }

  int shift = 0;
  int t = 1;
  while (t + 15 < len) {
    STEPM(0,  q1, 9,  1)  STEPM(1,  q2, 10, 2)  STEPM(2,  q3, 11, 3)
    STEPM(3,  q4, 12, 4)  STEPM(4,  q5, 13, 5)  STEPM(5,  q6, 14, 6)
    STEPM(6,  q7, 15, 7)  STEPM(7,  q0, 0,  8)  STEPM(8,  q1, 1,  9)
    STEPM(9,  q2, 2, 10)  STEPM(10, q3, 3, 11)  STEPM(11, q4, 4, 12)
    STEPM(12, q5, 5, 13)  STEPM(13, q6, 6, 14)  STEPM(14, q7, 7, 15)
    STEPM(15, q0, 8,  0)
    RENORM
    t += 16;
  }

  // tail: rows t..t+7 are in q1..q7,q0; rows t+8..t+14 are in LDS slots 9..15
  asm volatile("s_waitcnt vmcnt(0) lgkmcnt(0)" ::: "memory");
#define TAILR(i, R) if (t + (i) < len) { COMPUTE(R); }
#define TAILL(i, SLOT) if (t + (i) < len) { \
    f32x4 rT; DSR(rT, SLOT); \
    asm volatile("s_waitcnt lgkmcnt(0)" : "+v"(rT)); \
    COMPUTE(rT); }
  TAILR(0, q1)  TAILR(1, q2)  TAILR(2, q3)  TAILR(3, q4)
  TAILR(4, q5)  TAILR(5, q6)  TAILR(6, q7)  TAILR(7, q0)
  TAILL(8, 9)   TAILL(9, 10)  TAILL(10, 11) TAILL(11, 12)
  TAILL(12, 13) TAILL(13, 14) TAILL(14, 15)

  // final: -ln(alpha[2tl] + alpha[2tl-1]); per-wave readout (no cross-wave sync)
  A[w][4 * l + 0] = p0; A[w][4 * l + 1] = p1;
  A[w][4 * l + 2] = p2; A[w][4 * l + 3] = p3;
  if (l == 63) A[w][256] = p4;
  asm volatile("s_waitcnt lgkmcnt(0)" ::: "memory");
  if (l == 0) {
    const int ib = 2 * tl;
    const int il = (ib - 1) > 0 ? ib - 1 : 0;
    const float ab = A[w][ib];
    const float al = (tl > 0) ? A[w][il] : 0.0f;
    out[b] = -(__builtin_log2f(ab + al) + (float)(shift - BOOSTI * len)) * LN2F;
  }
}

extern "C" void kernel_launch(void* const* d_in, const int* in_sizes, int n_in,
                              void* d_out, int out_size, void* d_ws, size_t ws_size,
                              hipStream_t stream) {
  const float* logits  = (const float*)d_in[0];
  const int*   targets = (const int*)d_in[1];
  const int*   loglen  = (const int*)d_in[2];
  const int*   tgtlen  = (const int*)d_in[3];
  float* out = (float*)d_out;
  f32x4* Q = (f32x4*)d_ws;   // 32 MiB (proven sufficient in R8-R10)

  ctc_pre4<<<(B_ * T_) / 4, 256, 0, stream>>>(logits, targets, tgtlen, Q);
  ctc_dp4<<<B_ / 8, 512, 0, stream>>>(Q, targets, loglen, tgtlen, out);
}

// Round 14
// 84.009 us; speedup vs baseline: 1.4263x; 1.4263x over previous
//
#include <hip/hip_runtime.h>

enum { B_ = 32, T_ = 1024, V_ = 512, S_ = 128 };

static constexpr float K2   = 1.4426950408889634f;  // 1/ln2
static constexpr float LN2F = 0.6931471805599453f;
#define BOOSTI 6   // probs carry a 2^6 boost per emission so alpha drift ~0

typedef float f32x4 __attribute__((ext_vector_type(4)));
#define AS1 __attribute__((address_space(1)))
#define AS3 __attribute__((address_space(3)))

// DPP helpers
#define DPPI(x, ctrl) __builtin_amdgcn_update_dpp(0, (x), (ctrl), 0xF, 0xF, true)
#define DPPF(x, ctrl) __int_as_float(DPPI(__float_as_int(x), (ctrl)))
#define DPP_WSR1(x) DPPF((x), 0x138)   // lane l <- lane l-1, lane 0 <- 0

__device__ __forceinline__ float dpp_wave_max_l63(float x) {
  x = fmaxf(x, DPPF(x, 0xB1));   x = fmaxf(x, DPPF(x, 0x4E));
  x = fmaxf(x, DPPF(x, 0x124));  x = fmaxf(x, DPPF(x, 0x128));
  x = fmaxf(x, DPPF(x, 0x142));  x = fmaxf(x, DPPF(x, 0x143));
  return x;
}

// Kernel A: per (b,t) fused logsumexp + masked linear-prob table.
// Q[b][t][lane] = (pe1*v1, pe3*v3, pb*v0, pb*v2); row = 64 f32x4 = 1024 B.
__global__ __launch_bounds__(256) void ctc_pre4(
    const float* __restrict__ logits, const int* __restrict__ targets,
    const int* __restrict__ tgtlen, f32x4* __restrict__ Q) {
  const int w = threadIdx.x >> 6, l = threadIdx.x & 63;
  const int row = blockIdx.x * 4 + w;          // row = b*T + t
  const int b = row >> 10;
  const float* lrow = logits + (size_t)row * V_;
  const float4* r4 = (const float4*)lrow;
  float4 a = r4[l], c = r4[l + 64];
  float s = __builtin_exp2f(a.x * K2) + __builtin_exp2f(a.y * K2) +
            __builtin_exp2f(a.z * K2) + __builtin_exp2f(a.w * K2) +
            __builtin_exp2f(c.x * K2) + __builtin_exp2f(c.y * K2) +
            __builtin_exp2f(c.z * K2) + __builtin_exp2f(c.w * K2);
  #pragma unroll
  for (int off = 32; off; off >>= 1) s += __shfl_xor(s, off, 64);
  const float sh = (float)BOOSTI - __builtin_log2f(s);

  const int2 ee = ((const int2*)(targets + b * S_))[l];
  const int tl = tgtlen[b];
  const float lgb = __shfl(a.x, 0, 64);        // blank logit (elem 0)
  const float lg1 = lrow[ee.x];
  const float lg3 = lrow[ee.y];
  const float pb  = __builtin_exp2f(fmaf(lgb, K2, sh));
  const float pe1 = __builtin_exp2f(fmaf(lg1, K2, sh));
  const float pe3 = __builtin_exp2f(fmaf(lg3, K2, sh));
  const int smax = 2 * tl;
  f32x4 q;
  q.x = (4 * l + 1 <= smax) ? pe1 : 0.0f;
  q.y = (4 * l + 3 <= smax) ? pe3 : 0.0f;
  q.z = (4 * l     <= smax) ? pb  : 0.0f;
  q.w = (4 * l + 2 <= smax) ? pb  : 0.0f;
  Q[(size_t)row * 64 + l] = q;
}

// Kernel B: DP over the table. One wave per batch (R13 showed packing waves
// per CU contends ~77 cy/step of CU-shared resources). 32-slot LDS ring via
// global_load_lds; 8-deep mod-8 register file via ds_read_b128; one counted
// wait per 4 steps. State 256 is LANE-63-LOCAL (no readlanes in the loop):
// alpha[255] = lane63 p3, and when valid (tl=128) lane63's RX.w == pb.
__global__ __launch_bounds__(64, 1) void ctc_dp4(
    const f32x4* __restrict__ Q, const int* __restrict__ targets,
    const int* __restrict__ loglen, const int* __restrict__ tgtlen,
    float* __restrict__ out) {
  __shared__ f32x4 ring[32 * 64];   // 32 slots x 1 KiB
  __shared__ float A[257];
  const int b = blockIdx.x, l = threadIdx.x;
  const int len = loglen[b], tl = tgtlen[b];

  const int2 ee = ((const int2*)(targets + b * S_))[l];
  const int e1 = ee.x, e3 = ee.y;
  const int em1 = __shfl_up(e3, 1);
  const float m1 = ((l > 0) && (e1 != 0) && (e1 != em1)) ? 1.0f : 0.0f;
  const float m3 = ((e3 != 0) && (e3 != e1)) ? 1.0f : 0.0f;
  // state 256 mask, lane-63-local (exact: see header comment)
  const float v4l = ((l == 63) && (2 * tl >= 256)) ? 1.0f : 0.0f;
  const f32x4* Qb = Q + (size_t)b * T_ * 64;

  // t = 0 init straight from the table
  f32x4 qi = Qb[l];
  float p0 = (l == 0) ? qi.z : 0.0f;
  float p1 = (l == 0) ? qi.x : 0.0f;
  float p2 = 0.0f, p3 = 0.0f, p4 = 0.0f;

  const unsigned rbase = (unsigned)(uintptr_t)(AS3 char*)(void*)ring;
  const unsigned lofs  = rbase + (unsigned)l * 16u;

  asm volatile("s_waitcnt vmcnt(0) lgkmcnt(0)" ::: "memory");

#define GLL(ROW, SLOT) __builtin_amdgcn_global_load_lds( \
      (const AS1 void*)(const void*)(Qb + (size_t)(ROW) * 64 + l), \
      (AS3 void*)(void*)(&ring[(SLOT) * 64]), 16, 0, 0)

  // prologue: rows 1..32 -> slots (row & 31)
  GLL(1, 1);   GLL(2, 2);   GLL(3, 3);   GLL(4, 4);
  GLL(5, 5);   GLL(6, 6);   GLL(7, 7);   GLL(8, 8);
  GLL(9, 9);   GLL(10, 10); GLL(11, 11); GLL(12, 12);
  GLL(13, 13); GLL(14, 14); GLL(15, 15); GLL(16, 16);
  GLL(17, 17); GLL(18, 18); GLL(19, 19); GLL(20, 20);
  GLL(21, 21); GLL(22, 22); GLL(23, 23); GLL(24, 24);
  GLL(25, 25); GLL(26, 26); GLL(27, 27); GLL(28, 28);
  GLL(29, 29); GLL(30, 30); GLL(31, 31); GLL(32, 0);
  asm volatile("s_waitcnt vmcnt(24)" ::: "memory");   // rows 1..8 landed

  // 8-deep register file: q<g> holds the row with (row & 7) == g
  f32x4 q0, q1, q2, q3, q4, q5, q6, q7;
#define DSR(dst, SLOT) asm volatile("ds_read_b128 %0, %1" \
      : "=&v"(dst) : "v"(lofs + (unsigned)(SLOT) * 1024u))
  DSR(q1, 1); DSR(q2, 2); DSR(q3, 3); DSR(q4, 4);
  DSR(q5, 5); DSR(q6, 6); DSR(q7, 7); DSR(q0, 8);

#define COMPUTE(RX) { \
    const float n1_  = DPP_WSR1(p3); \
    const float w0_ = (p0 + n1_) * RX.z; \
    const float w1_ = (p0 + p1 + n1_ * m1) * RX.x; \
    const float w2_ = (p1 + p2) * RX.w; \
    const float w3_ = (p2 + p3 + p1 * m3) * RX.y; \
    const float w4_ = (p4 + p3) * RX.w * v4l; \
    p0 = w0_; p1 = w1_; p2 = w2_; p3 = w3_; p4 = w4_; \
  }

  // ONE wait per 4-step group. Counting (group start = step r, t ≡ 1 mod 32):
  //  vm: outstanding ≤24, wait to 20 -> GLLs for rows ≤ r+11 landed
  //      (this group's DSRs read rows r+8..r+11)
  //  lgkm: outstanding 8, wait to 4 -> DSRs for rows ≤ r+3 done
  //      (this group consumes rows r..r+3)
#define WAITG(RA, RB, RC, RD) asm volatile("s_waitcnt vmcnt(20) lgkmcnt(4)" \
    : "+v"(RA), "+v"(RB), "+v"(RC), "+v"(RD) :: "memory");

  // sub-step i (row r = t+i): consume q[(1+i)&7]; refill slot (1+i)&31 with
  // row r+32; ds_read row r+8 from slot (9+i)&31 into the same register.
#define SUB(i, R) { \
    COMPUTE(R); \
    int row_ = t + (i) + 32; if (row_ > T_ - 1) row_ = T_ - 1; \
    GLL(row_, ((i) + 1) & 31); \
    DSR(R, ((i) + 9) & 31); \
  }

#define RENORM { \
    float m_ = fmaxf(fmaxf(fmaxf(p0, p1), fmaxf(p2, p3)), p4); \
    m_ = dpp_wave_max_l63(m_); \
    const int wm_ = __builtin_amdgcn_readlane(__float_as_int(m_), 63); \
    const int e_ = (wm_ >> 23) & 0xFF; \
    const float sc_ = __int_as_float((254 - e_) << 23); \
    p0 *= sc_; p1 *= sc_; p2 *= sc_; p3 *= sc_; p4 *= sc_; \
    shift += e_ - 127; \
  }

  int shift = 0;
  int t = 1;
  while (t + 31 < len) {          // chunk of 32 rows, all < len
    WAITG(q1, q2, q3, q4) SUB(0,  q1) SUB(1,  q2) SUB(2,  q3) SUB(3,  q4)
    WAITG(q5, q6, q7, q0) SUB(4,  q5) SUB(5,  q6) SUB(6,  q7) SUB(7,  q0)
    WAITG(q1, q2, q3, q4) SUB(8,  q1) SUB(9,  q2) SUB(10, q3) SUB(11, q4)
    WAITG(q5, q6, q7, q0) SUB(12, q5) SUB(13, q6) SUB(14, q7) SUB(15, q0)
    RENORM
    WAITG(q1, q2, q3, q4) SUB(16, q1) SUB(17, q2) SUB(18, q3) SUB(19, q4)
    WAITG(q5, q6, q7, q0) SUB(20, q5) SUB(21, q6) SUB(22, q7) SUB(23, q0)
    WAITG(q1, q2, q3, q4) SUB(24, q1) SUB(25, q2) SUB(26, q3) SUB(27, q4)
    WAITG(q5, q6, q7, q0) SUB(28, q5) SUB(29, q6) SUB(30, q7) SUB(31, q0)
    RENORM
    t += 32;
  }

  // tail: rows t..t+7 in q1..q7,q0; rows t+8..t+30 in slots 9..31 (t ≡ 1 mod 32)
  asm volatile("s_waitcnt vmcnt(0) lgkmcnt(0)" ::: "memory");
#define TAILR(i, R) if (t + (i) < len) { COMPUTE(R); }
#define TAILL(i, SLOT) if (t + (i) < len) { \
    f32x4 rT; DSR(rT, SLOT); \
    asm volatile("s_waitcnt lgkmcnt(0)" : "+v"(rT)); \
    COMPUTE(rT); }
  TAILR(0, q1)  TAILR(1, q2)  TAILR(2, q3)  TAILR(3, q4)
  TAILR(4, q5)  TAILR(5, q6)  TAILR(6, q7)  TAILR(7, q0)
  TAILL(8, 9)   TAILL(9, 10)  TAILL(10, 11) TAILL(11, 12)
  TAILL(12, 13) TAILL(13, 14) TAILL(14, 15) TAILL(15, 16)
  TAILL(16, 17) TAILL(17, 18) TAILL(18, 19) TAILL(19, 20)
  TAILL(20, 21) TAILL(21, 22) TAILL(22, 23) TAILL(23, 24)
  TAILL(24, 25) TAILL(25, 26) TAILL(26, 27) TAILL(27, 28)
  TAILL(28, 29) TAILL(29, 30) TAILL(30, 31)

  // final: -ln(alpha[2tl] + alpha[2tl-1]) with scale accounting
  A[4 * l + 0] = p0; A[4 * l + 1] = p1;
  A[4 * l + 2] = p2; A[4 * l + 3] = p3;
  if (l == 63) A[256] = p4;
  __syncthreads();
  if (l == 0) {
    const int ib = 2 * tl;
    const int il = (ib - 1) > 0 ? ib - 1 : 0;
    const float ab = A[ib];
    const float al = (tl > 0) ? A[il] : 0.0f;
    out[b] = -(__builtin_log2f(ab + al) + (float)(shift - BOOSTI * len)) * LN2F;
  }
}

extern "C" void kernel_launch(void* const* d_in, const int* in_sizes, int n_in,
                              void* d_out, int out_size, void* d_ws, size_t ws_size,
                              hipStream_t stream) {
  const float* logits  = (const float*)d_in[0];
  const int*   targets = (const int*)d_in[1];
  const int*   loglen  = (const int*)d_in[2];
  const int*   tgtlen  = (const int*)d_in[3];
  float* out = (float*)d_out;
  f32x4* Q = (f32x4*)d_ws;   // 32 MiB (proven sufficient in R8-R10)

  ctc_pre4<<<(B_ * T_) / 4, 256, 0, stream>>>(logits, targets, tgtlen, Q);
  ctc_dp4<<<B_, 64, 0, stream>>>(Q, targets, loglen, tgtlen, out);
}

// Round 17
// 66.347 us; speedup vs baseline: 1.8060x; 1.2662x over previous
//
#include <hip/hip_runtime.h>

enum { B_ = 32, T_ = 1024, V_ = 512, S_ = 128 };

static constexpr float K2   = 1.4426950408889634f;  // 1/ln2
static constexpr float LN2F = 0.6931471805599453f;
#define BOOSTI 6   // probs carry a 2^6 boost per emission so alpha drift ~0

typedef float f32x4 __attribute__((ext_vector_type(4)));
#define AS1 __attribute__((address_space(1)))
#define AS3 __attribute__((address_space(3)))

// DPP helpers
#define DPPI(x, ctrl) __builtin_amdgcn_update_dpp(0, (x), (ctrl), 0xF, 0xF, true)
#define DPPF(x, ctrl) __int_as_float(DPPI(__float_as_int(x), (ctrl)))
#define DPP_WSR1(x) DPPF((x), 0x138)   // lane l <- lane l-1, lane 0 <- 0

__device__ __forceinline__ float dpp_wave_max_l63(float x) {
  x = fmaxf(x, DPPF(x, 0xB1));   x = fmaxf(x, DPPF(x, 0x4E));
  x = fmaxf(x, DPPF(x, 0x124));  x = fmaxf(x, DPPF(x, 0x128));
  x = fmaxf(x, DPPF(x, 0x142));  x = fmaxf(x, DPPF(x, 0x143));
  return x;
}

// Kernel A: per (b,t) fused logsumexp + masked linear-prob table.
// Q[b][t][lane] = (pe1*v1, pe3*v3, pb*v0, pb*v2); row = 64 f32x4 = 1024 B.
__global__ __launch_bounds__(256) void ctc_pre4(
    const float* __restrict__ logits, const int* __restrict__ targets,
    const int* __restrict__ tgtlen, f32x4* __restrict__ Q) {
  const int w = threadIdx.x >> 6, l = threadIdx.x & 63;
  const int row = blockIdx.x * 4 + w;          // row = b*T + t
  const int b = row >> 10;
  const float* lrow = logits + (size_t)row * V_;
  const float4* r4 = (const float4*)lrow;
  float4 a = r4[l], c = r4[l + 64];
  float s = __builtin_exp2f(a.x * K2) + __builtin_exp2f(a.y * K2) +
            __builtin_exp2f(a.z * K2) + __builtin_exp2f(a.w * K2) +
            __builtin_exp2f(c.x * K2) + __builtin_exp2f(c.y * K2) +
            __builtin_exp2f(c.z * K2) + __builtin_exp2f(c.w * K2);
  #pragma unroll
  for (int off = 32; off; off >>= 1) s += __shfl_xor(s, off, 64);
  const float sh = (float)BOOSTI - __builtin_log2f(s);

  const int2 ee = ((const int2*)(targets + b * S_))[l];
  const int tl = tgtlen[b];
  const float lgb = __shfl(a.x, 0, 64);        // blank logit (elem 0)
  const float lg1 = lrow[ee.x];
  const float lg3 = lrow[ee.y];
  const float pb  = __builtin_exp2f(fmaf(lgb, K2, sh));
  const float pe1 = __builtin_exp2f(fmaf(lg1, K2, sh));
  const float pe3 = __builtin_exp2f(fmaf(lg3, K2, sh));
  const int smax = 2 * tl;
  f32x4 q;
  q.x = (4 * l + 1 <= smax) ? pe1 : 0.0f;
  q.y = (4 * l + 3 <= smax) ? pe3 : 0.0f;
  q.z = (4 * l     <= smax) ? pb  : 0.0f;
  q.w = (4 * l + 2 <= smax) ? pb  : 0.0f;
  Q[(size_t)row * 64 + l] = q;
}

// Kernel B: producer-consumer wave specialization. Wave 1 stages 32-row
// chunks into a double-buffered LDS ring via global_load_lds + vmcnt(0) +
// flag; wave 0's DP loop is pure {ds_read(imm offset) + lgkm wait + COMPUTE}
// with zero VMEM and zero per-step address arithmetic.
__global__ __launch_bounds__(128, 1) void ctc_dp7(
    const f32x4* __restrict__ Q, const int* __restrict__ targets,
    const int* __restrict__ loglen, const int* __restrict__ tgtlen,
    float* __restrict__ out) {
  __shared__ f32x4 buf[2][32 * 64];   // 2 x 32 KiB chunks
  __shared__ int flag_ready[2];       // generation counters (chunk index + 1)
  __shared__ int flag_done[2];
  __shared__ float A[257];
  const int wv = threadIdx.x >> 6, l = threadIdx.x & 63;
  const int b = blockIdx.x;
  const int len = loglen[b], tl = tgtlen[b];
  const int nch = (len - 1 + 31) >> 5;          // chunks of 32 rows from t=1
  const f32x4* Qb = Q + (size_t)b * T_ * 64;

  if (threadIdx.x == 0) {
    flag_ready[0] = 0; flag_ready[1] = 0;
    flag_done[0] = 0;  flag_done[1] = 0;
  }
  __syncthreads();

  if (wv == 1) {
    // ---------------- producer ----------------
    for (int c = 0; c < nch; ++c) {
      if (c >= 2) {
        while (((volatile int*)flag_done)[c & 1] < c - 1)
          __builtin_amdgcn_s_sleep(1);
      }
      const int r0 = 1 + 32 * c;
      #pragma unroll
      for (int i = 0; i < 32; ++i) {
        int row = r0 + i; if (row > T_ - 1) row = T_ - 1;
        __builtin_amdgcn_global_load_lds(
            (const AS1 void*)(const void*)(Qb + (size_t)row * 64 + l),
            (AS3 void*)(void*)(&buf[c & 1][i * 64]), 16, 0, 0);
      }
      asm volatile("s_waitcnt vmcnt(0)" ::: "memory");
      if (l == 0) ((volatile int*)flag_ready)[c & 1] = c + 1;
    }
    return;
  }

  // ---------------- consumer ----------------
  const int2 ee = ((const int2*)(targets + b * S_))[l];
  const int e1 = ee.x, e3 = ee.y;
  const int em1 = __shfl_up(e3, 1);
  const float m1 = ((l > 0) && (e1 != 0) && (e1 != em1)) ? 1.0f : 0.0f;
  const float m3 = ((e3 != 0) && (e3 != e1)) ? 1.0f : 0.0f;
  const float v4l = ((l == 63) && (2 * tl >= 256)) ? 1.0f : 0.0f;

  f32x4 qi = Qb[l];                    // t = 0 init
  float p0 = (l == 0) ? qi.z : 0.0f;
  float p1 = (l == 0) ? qi.x : 0.0f;
  float p2 = 0.0f, p3 = 0.0f, p4 = 0.0f;

  const unsigned bufbase = (unsigned)(uintptr_t)(AS3 char*)(void*)&buf[0][0];

  f32x4 q0, q1, q2, q3, q4, q5, q6, q7;
#define DSRO(R, O) asm volatile("ds_read_b128 %0, %1 offset:" #O \
      : "=&v"(R) : "v"(vb))
#define WTL(R, N) asm volatile("s_waitcnt lgkmcnt(" #N ")" : "+v"(R))

#define COMPUTE(RX) { \
    const float n1_  = DPP_WSR1(p3); \
    const float w0_ = (p0 + n1_) * RX.z; \
    const float w1_ = (p0 + p1 + n1_ * m1) * RX.x; \
    const float w2_ = (p1 + p2) * RX.w; \
    const float w3_ = (p2 + p3 + p1 * m3) * RX.y; \
    const float w4_ = (p4 + p3) * RX.w * v4l; \
    p0 = w0_; p1 = w1_; p2 = w2_; p3 = w3_; p4 = w4_; \
  }

#define RENORM { \
    float m_ = fmaxf(fmaxf(fmaxf(p0, p1), fmaxf(p2, p3)), p4); \
    m_ = dpp_wave_max_l63(m_); \
    const int wm_ = __builtin_amdgcn_readlane(__float_as_int(m_), 63); \
    const int e_ = (wm_ >> 23) & 0xFF; \
    const float sc_ = __int_as_float((254 - e_) << 23); \
    p0 *= sc_; p1 *= sc_; p2 *= sc_; p3 *= sc_; p4 *= sc_; \
    shift += e_ - 127; \
  }

  // full-chunk step: consume reg (row i), reissue row i+8 (i = 0..23)
#define FS(R, O)  { WTL(R, 7); COMPUTE(R); DSRO(R, O); }
  // drain steps (i = 24..31)
#define FD(R, N)  { WTL(R, N); COMPUTE(R); }
  // guarded tail steps
#define TS(R, O, i)  { WTL(R, 7); if (t0 + (i) < len) COMPUTE(R); DSRO(R, O); }
#define TD(R, N, i)  { WTL(R, N); if (t0 + (i) < len) COMPUTE(R); }

  int shift = 0;
  for (int c = 0; c < nch; ++c) {
    const int t0 = 1 + 32 * c;
    while (((volatile int*)flag_ready)[c & 1] < c + 1)
      __builtin_amdgcn_s_sleep(1);
    const unsigned vb = bufbase + (unsigned)(c & 1) * 32768u + (unsigned)l * 16u;

    // prologue: rows 0..7 of chunk
    DSRO(q0, 0);    DSRO(q1, 1024); DSRO(q2, 2048); DSRO(q3, 3072);
    DSRO(q4, 4096); DSRO(q5, 5120); DSRO(q6, 6144); DSRO(q7, 7168);

    if (t0 + 31 < len) {
      FS(q0, 8192)  FS(q1, 9216)  FS(q2, 10240) FS(q3, 11264)
      FS(q4, 12288) FS(q5, 13312) FS(q6, 14336) FS(q7, 15360)
      FS(q0, 16384) FS(q1, 17408) FS(q2, 18432) FS(q3, 19456)
      FS(q4, 20480) FS(q5, 21504) FS(q6, 22528) FS(q7, 23552)
      RENORM
      FS(q0, 24576) FS(q1, 25600) FS(q2, 26624) FS(q3, 27648)
      FS(q4, 28672) FS(q5, 29696) FS(q6, 30720) FS(q7, 31744)
      FD(q0, 7) FD(q1, 6) FD(q2, 5) FD(q3, 4)
      FD(q4, 3) FD(q5, 2) FD(q6, 1) FD(q7, 0)
      RENORM
    } else {
      TS(q0, 8192, 0)   TS(q1, 9216, 1)   TS(q2, 10240, 2)  TS(q3, 11264, 3)
      TS(q4, 12288, 4)  TS(q5, 13312, 5)  TS(q6, 14336, 6)  TS(q7, 15360, 7)
      TS(q0, 16384, 8)  TS(q1, 17408, 9)  TS(q2, 18432, 10) TS(q3, 19456, 11)
      TS(q4, 20480, 12) TS(q5, 21504, 13) TS(q6, 22528, 14) TS(q7, 23552, 15)
      TS(q0, 24576, 16) TS(q1, 25600, 17) TS(q2, 26624, 18) TS(q3, 27648, 19)
      TS(q4, 28672, 20) TS(q5, 29696, 21) TS(q6, 30720, 22) TS(q7, 31744, 23)
      TD(q0, 7, 24) TD(q1, 6, 25) TD(q2, 5, 26) TD(q3, 4, 27)
      TD(q4, 3, 28) TD(q5, 2, 29) TD(q6, 1, 30) TD(q7, 0, 31)
    }

    asm volatile("s_waitcnt lgkmcnt(0)" ::: "memory");
    if (l == 0) ((volatile int*)flag_done)[c & 1] = c + 1;
  }

  // final: -ln(alpha[2tl] + alpha[2tl-1]) with scale accounting (same wave)
  A[4 * l + 0] = p0; A[4 * l + 1] = p1;
  A[4 * l + 2] = p2; A[4 * l + 3] = p3;
  if (l == 63) A[256] = p4;
  asm volatile("s_waitcnt lgkmcnt(0)" ::: "memory");
  if (l == 0) {
    const int ib = 2 * tl;
    const int il = (ib - 1) > 0 ? ib - 1 : 0;
    const float ab = A[ib];
    const float al = (tl > 0) ? A[il] : 0.0f;
    out[b] = -(__builtin_log2f(ab + al) + (float)(shift - BOOSTI * len)) * LN2F;
  }
}

extern "C" void kernel_launch(void* const* d_in, const int* in_sizes, int n_in,
                              void* d_out, int out_size, void* d_ws, size_t ws_size,
                              hipStream_t stream) {
  const float* logits  = (const float*)d_in[0];
  const int*   targets = (const int*)d_in[1];
  const int*   loglen  = (const int*)d_in[2];
  const int*   tgtlen  = (const int*)d_in[3];
  float* out = (float*)d_out;
  f32x4* Q = (f32x4*)d_ws;   // 32 MiB (proven sufficient in R8-R14)

  ctc_pre4<<<(B_ * T_) / 4, 256, 0, stream>>>(logits, targets, tgtlen, Q);
  ctc_dp7<<<B_, 128, 0, stream>>>(Q, targets, loglen, tgtlen, out);
}